// Round 3
// baseline (735.525 us; speedup 1.0000x reference)
//
#include <hip/hip_runtime.h>

namespace {

constexpr int H = 1024;
constexpr int W = 1024;
constexpr int PLANE = H * W;
constexpr int CIN = 18;     // total input channels
constexpr int C = 8;        // filterable channels
constexpr int TX = 16;
constexpr int TY = 16;      // threads in y; each thread does 2 vertical pixels
constexpr int TILE_H = 32;  // output rows per block
constexpr int SW = TX + 6;      // 22 halo width
constexpr int SH = TILE_H + 6;  // 38 halo height
constexpr int NPOS = SW * SH;   // 836 positions
constexpr float LOG2E = 1.44269504088896340736f;

typedef _Float16 half2_t __attribute__((ext_vector_type(2)));
typedef _Float16 half8_t __attribute__((ext_vector_type(8)));

__device__ __forceinline__ float dot2acc(half2_t a, half2_t b, float c) {
#if defined(__has_builtin)
#if __has_builtin(__builtin_amdgcn_fdot2)
    return __builtin_amdgcn_fdot2(a, b, c, false);
#else
    return fmaf((float)a[0], (float)b[0], fmaf((float)a[1], (float)b[1], c));
#endif
#else
    return fmaf((float)a[0], (float)b[0], fmaf((float)a[1], (float)b[1], c));
#endif
}

__device__ __forceinline__ float fast_exp2(float x) {
#if defined(__has_builtin)
#if __has_builtin(__builtin_amdgcn_exp2f)
    return __builtin_amdgcn_exp2f(x);
#else
    return exp2f(x);
#endif
#else
    return exp2f(x);
#endif
}

template<bool INTERIOR>
__device__ __forceinline__ void run_tile(const float* __restrict__ inb,
                                         float* __restrict__ outb,
                                         half8_t* __restrict__ tile,
                                         float* __restrict__ msk,
                                         int gy0, int gx0)
{
    const int tx = threadIdx.x, ty = threadIdx.y;
    const int tid = ty * TX + tx;

    const int o0 = gy0 + 2 * ty;      // first output row of this thread
    const int gx = gx0 + tx;
    const int pofs0 = o0 * W + gx;    // pixel 0; pixel 1 = pofs0 + W

    // ---- per-pixel params for BOTH pixels first (their global latency
    // overlaps the staging loop + barrier). log2e folded in.
    half2_t rp01_0, rp23_0, rp45_0, rp67_0;
    half2_t rp01_1, rp23_1, rp45_1, rp67_1;
    float sxf0, syf0, sxf1, syf1;
    {
        const float* pp = inb + (size_t)C * PLANE + pofs0;
        float r0[C], r1[C];
#pragma unroll
        for (int c = 0; c < C; ++c) {
            float p0 = pp[(size_t)c * PLANE];
            float p1 = pp[(size_t)c * PLANE + W];
            r0[c] = -(p0 * p0) * LOG2E;
            r1[c] = -(p1 * p1) * LOG2E;
        }
        float px0 = pp[(size_t)8 * PLANE];
        float py0 = pp[(size_t)9 * PLANE];
        float px1 = pp[(size_t)8 * PLANE + W];
        float py1 = pp[(size_t)9 * PLANE + W];
        rp01_0 = half2_t{(_Float16)r0[0], (_Float16)r0[1]};
        rp23_0 = half2_t{(_Float16)r0[2], (_Float16)r0[3]};
        rp45_0 = half2_t{(_Float16)r0[4], (_Float16)r0[5]};
        rp67_0 = half2_t{(_Float16)r0[6], (_Float16)r0[7]};
        rp01_1 = half2_t{(_Float16)r1[0], (_Float16)r1[1]};
        rp23_1 = half2_t{(_Float16)r1[2], (_Float16)r1[3]};
        rp45_1 = half2_t{(_Float16)r1[4], (_Float16)r1[5]};
        rp67_1 = half2_t{(_Float16)r1[6], (_Float16)r1[7]};
        sxf0 = -(px0 * px0) * LOG2E;  syf0 = -(py0 * py0) * LOG2E;
        sxf1 = -(px1 * px1) * LOG2E;  syf1 = -(py1 * py1) * LOG2E;
    }

    // ---- stage: fixed-trip unrolled so all records' loads issue together
#pragma unroll
    for (int it = 0; it < 4; ++it) {
        int idx = tid + it * (TX * TY);
        if (idx < NPOS) {
            int y = idx / SW;
            int x = idx - y * SW;
            int sy_ = gy0 + y - 3;
            int sx_ = gx0 + x - 3;
            half8_t hv;
            if (INTERIOR || ((unsigned)sy_ < (unsigned)H && (unsigned)sx_ < (unsigned)W)) {
                const float* p = inb + sy_ * W + sx_;
#pragma unroll
                for (int c = 0; c < C; ++c) hv[c] = (_Float16)p[(size_t)c * PLANE];
                if (!INTERIOR) msk[idx] = 1.0f;
            } else {
#pragma unroll
                for (int c = 0; c < C; ++c) hv[c] = (_Float16)0.0f;
                msk[idx] = 0.0f;
            }
            tile[idx] = hv;
        }
    }
    __syncthreads();

    // halo-row origin for this thread: window of px0 starts at halo row 2*ty
    const half8_t* lp = tile + (2 * ty) * SW + tx;
    const half8_t fc0 = lp[3 * SW + 3];  // center of px0
    const half8_t fc1 = lp[4 * SW + 3];  // center of px1

    float a00 = 0.f, a01 = 0.f, a02 = 0.f, ws0 = 0.f;
    float a10 = 0.f, a11 = 0.f, a12 = 0.f, ws1 = 0.f;

    half8_t q0_, q1_, q2_, q3_, q4_, q5_, q6_;

#define LOADROW(I) do { const half8_t* lq_ = lp + (I) * SW;              \
        q0_ = lq_[0]; q1_ = lq_[1]; q2_ = lq_[2]; q3_ = lq_[3];          \
        q4_ = lq_[4]; q5_ = lq_[5]; q6_ = lq_[6]; } while (0)

#define PIXA(Q, J) do {                                                  \
        half8_t d_ = (Q) - fc0;                                          \
        half8_t dd_ = d_ * d_;                                           \
        float lw_ = fmaf((float)(((J) - 3) * ((J) - 3)), sxf0, rs0_);    \
        lw_ = dot2acc(__builtin_shufflevector(dd_, dd_, 0, 1), rp01_0, lw_); \
        lw_ = dot2acc(__builtin_shufflevector(dd_, dd_, 2, 3), rp23_0, lw_); \
        lw_ = dot2acc(__builtin_shufflevector(dd_, dd_, 4, 5), rp45_0, lw_); \
        lw_ = dot2acc(__builtin_shufflevector(dd_, dd_, 6, 7), rp67_0, lw_); \
        float w_ = fast_exp2(lw_);                                       \
        if (!INTERIOR) w_ *= mrow_[(J)];                                 \
        ws0 += w_;                                                       \
        a00 = fmaf(w_, (float)(Q)[0], a00);                              \
        a01 = fmaf(w_, (float)(Q)[1], a01);                              \
        a02 = fmaf(w_, (float)(Q)[2], a02);                              \
    } while (0)

#define PIXB(Q, J) do {                                                  \
        half8_t d_ = (Q) - fc1;                                          \
        half8_t dd_ = d_ * d_;                                           \
        float lw_ = fmaf((float)(((J) - 3) * ((J) - 3)), sxf1, rs1_);    \
        lw_ = dot2acc(__builtin_shufflevector(dd_, dd_, 0, 1), rp01_1, lw_); \
        lw_ = dot2acc(__builtin_shufflevector(dd_, dd_, 2, 3), rp23_1, lw_); \
        lw_ = dot2acc(__builtin_shufflevector(dd_, dd_, 4, 5), rp45_1, lw_); \
        lw_ = dot2acc(__builtin_shufflevector(dd_, dd_, 6, 7), rp67_1, lw_); \
        float w_ = fast_exp2(lw_);                                       \
        if (!INTERIOR) w_ *= mrow_[(J)];                                 \
        ws1 += w_;                                                       \
        a10 = fmaf(w_, (float)(Q)[0], a10);                              \
        a11 = fmaf(w_, (float)(Q)[1], a11);                              \
        a12 = fmaf(w_, (float)(Q)[2], a12);                              \
    } while (0)

#define ROW_COMMON(I)                                                    \
        LOADROW(I);                                                      \
        const float* mrow_ = msk + (2 * ty + (I)) * SW + tx;             \
        (void)mrow_;

#define ROW_FIRST(I) {                                                   \
        ROW_COMMON(I)                                                    \
        const float rs0_ = syf0 * (float)(((I) - 3) * ((I) - 3));        \
        PIXA(q0_, 0); PIXA(q1_, 1); PIXA(q2_, 2); PIXA(q3_, 3);          \
        PIXA(q4_, 4); PIXA(q5_, 5); PIXA(q6_, 6);                        \
    }

#define ROW_BOTH(I) {                                                    \
        ROW_COMMON(I)                                                    \
        const float rs0_ = syf0 * (float)(((I) - 3) * ((I) - 3));        \
        const float rs1_ = syf1 * (float)(((I) - 4) * ((I) - 4));        \
        PIXA(q0_, 0); PIXB(q0_, 0); PIXA(q1_, 1); PIXB(q1_, 1);          \
        PIXA(q2_, 2); PIXB(q2_, 2); PIXA(q3_, 3); PIXB(q3_, 3);          \
        PIXA(q4_, 4); PIXB(q4_, 4); PIXA(q5_, 5); PIXB(q5_, 5);          \
        PIXA(q6_, 6); PIXB(q6_, 6);                                      \
    }

#define ROW_LAST(I) {                                                    \
        ROW_COMMON(I)                                                    \
        const float rs1_ = syf1 * (float)(((I) - 4) * ((I) - 4));        \
        PIXB(q0_, 0); PIXB(q1_, 1); PIXB(q2_, 2); PIXB(q3_, 3);          \
        PIXB(q4_, 4); PIXB(q5_, 5); PIXB(q6_, 6);                        \
    }

    ROW_FIRST(0)
    ROW_BOTH(1)
    ROW_BOTH(2)
    ROW_BOTH(3)
    ROW_BOTH(4)
    ROW_BOTH(5)
    ROW_BOTH(6)
    ROW_LAST(7)

#undef ROW_LAST
#undef ROW_BOTH
#undef ROW_FIRST
#undef ROW_COMMON
#undef PIXB
#undef PIXA
#undef LOADROW

    const float inv0 = 1.0f / ws0;
    const float inv1 = 1.0f / ws1;
    outb[pofs0]                 = a00 * inv0;
    outb[PLANE + pofs0]         = a01 * inv0;
    outb[2 * PLANE + pofs0]     = a02 * inv0;
    outb[pofs0 + W]             = a10 * inv1;
    outb[PLANE + pofs0 + W]     = a11 * inv1;
    outb[2 * PLANE + pofs0 + W] = a12 * inv1;
}

// 2 vertical px/thread: windows share 6/8 halo rows -> ds_read/px ~halved,
// 2 independent exp-chains per loaded q (ILP covers LDS latency), staging
// recs/px 1.89->1.63, half the blocks. All named regs (R1: arrays->scratch).
__global__ __launch_bounds__(TX * TY, 4) void bilateral_kernel(const float* __restrict__ in,
                                                               float* __restrict__ out)
{
    __shared__ __align__(16) half8_t tile[NPOS];
    __shared__ float msk[NPOS];
    const int b = blockIdx.z;
    const int gx0 = blockIdx.x * TX;
    const int gy0 = blockIdx.y * TILE_H;
    const float* inb = in + (size_t)b * CIN * PLANE;
    float* outb = out + (size_t)b * 3 * PLANE;

    const bool interior = (gx0 >= 3) && (gx0 + TX + 3 <= W) &&
                          (gy0 >= 3) && (gy0 + TILE_H + 3 <= H);
    if (interior)
        run_tile<true>(inb, outb, tile, msk, gy0, gx0);
    else
        run_tile<false>(inb, outb, tile, msk, gy0, gx0);
}

} // namespace

extern "C" void kernel_launch(void* const* d_in, const int* in_sizes, int n_in,
                              void* d_out, int out_size, void* d_ws, size_t ws_size,
                              hipStream_t stream)
{
    const float* in = (const float*)d_in[0];
    float* out = (float*)d_out;
    dim3 grid(W / TX, H / TILE_H, 2);
    dim3 block(TX, TY);
    hipLaunchKernelGGL(bilateral_kernel, grid, block, 0, stream, in, out);
}

// Round 4
// 424.209 us; speedup vs baseline: 1.7339x; 1.7339x over previous
//
#include <hip/hip_runtime.h>

namespace {

constexpr int H = 1024;
constexpr int W = 1024;
constexpr int PLANE = H * W;
constexpr int CIN = 18;     // total input channels
constexpr int C = 8;        // filterable channels
constexpr int TX = 16;
constexpr int TY = 16;      // threads in y; each thread does 2 vertical pixels
constexpr int TILE_H = 32;  // output rows per block
constexpr int SW = TX + 6;      // 22 halo width
constexpr int SH = TILE_H + 6;  // 38 halo height
constexpr int NPOS = SW * SH;   // 836 positions
constexpr float LOG2E = 1.44269504088896340736f;

typedef _Float16 half2_t __attribute__((ext_vector_type(2)));
typedef _Float16 half8_t __attribute__((ext_vector_type(8)));

__device__ __forceinline__ float dot2acc(half2_t a, half2_t b, float c) {
#if defined(__has_builtin)
#if __has_builtin(__builtin_amdgcn_fdot2)
    return __builtin_amdgcn_fdot2(a, b, c, false);
#else
    return fmaf((float)a[0], (float)b[0], fmaf((float)a[1], (float)b[1], c));
#endif
#else
    return fmaf((float)a[0], (float)b[0], fmaf((float)a[1], (float)b[1], c));
#endif
}

__device__ __forceinline__ float fast_exp2(float x) {
#if defined(__has_builtin)
#if __has_builtin(__builtin_amdgcn_exp2f)
    return __builtin_amdgcn_exp2f(x);
#else
    return exp2f(x);
#endif
#else
    return exp2f(x);
#endif
}

template<bool INTERIOR>
__device__ __forceinline__ void run_tile(const float* __restrict__ inb,
                                         float* __restrict__ outb,
                                         half8_t* __restrict__ tile,
                                         float* __restrict__ msk,
                                         int gy0, int gx0)
{
    const int tx = threadIdx.x, ty = threadIdx.y;
    const int tid = ty * TX + tx;

    const int o0 = gy0 + 2 * ty;      // first output row of this thread
    const int gx = gx0 + tx;
    const int pofs0 = o0 * W + gx;    // pixel 0; pixel 1 = pofs0 + W

    // ---- per-pixel params for BOTH pixels first (their global latency
    // overlaps the staging loop + barrier). log2e folded in.
    half2_t rp01_0, rp23_0, rp45_0, rp67_0;
    half2_t rp01_1, rp23_1, rp45_1, rp67_1;
    float sxf0, syf0, sxf1, syf1;
    {
        const float* pp = inb + (size_t)C * PLANE + pofs0;
        float r0[C], r1[C];
#pragma unroll
        for (int c = 0; c < C; ++c) {
            float p0 = pp[(size_t)c * PLANE];
            float p1 = pp[(size_t)c * PLANE + W];
            r0[c] = -(p0 * p0) * LOG2E;
            r1[c] = -(p1 * p1) * LOG2E;
        }
        float px0 = pp[(size_t)8 * PLANE];
        float py0 = pp[(size_t)9 * PLANE];
        float px1 = pp[(size_t)8 * PLANE + W];
        float py1 = pp[(size_t)9 * PLANE + W];
        rp01_0 = half2_t{(_Float16)r0[0], (_Float16)r0[1]};
        rp23_0 = half2_t{(_Float16)r0[2], (_Float16)r0[3]};
        rp45_0 = half2_t{(_Float16)r0[4], (_Float16)r0[5]};
        rp67_0 = half2_t{(_Float16)r0[6], (_Float16)r0[7]};
        rp01_1 = half2_t{(_Float16)r1[0], (_Float16)r1[1]};
        rp23_1 = half2_t{(_Float16)r1[2], (_Float16)r1[3]};
        rp45_1 = half2_t{(_Float16)r1[4], (_Float16)r1[5]};
        rp67_1 = half2_t{(_Float16)r1[6], (_Float16)r1[7]};
        sxf0 = -(px0 * px0) * LOG2E;  syf0 = -(py0 * py0) * LOG2E;
        sxf1 = -(px1 * px1) * LOG2E;  syf1 = -(py1 * py1) * LOG2E;
    }

    // ---- stage: fixed-trip unrolled so all records' loads issue together
#pragma unroll
    for (int it = 0; it < 4; ++it) {
        int idx = tid + it * (TX * TY);
        if (idx < NPOS) {
            int y = idx / SW;
            int x = idx - y * SW;
            int sy_ = gy0 + y - 3;
            int sx_ = gx0 + x - 3;
            half8_t hv;
            if (INTERIOR || ((unsigned)sy_ < (unsigned)H && (unsigned)sx_ < (unsigned)W)) {
                const float* p = inb + sy_ * W + sx_;
#pragma unroll
                for (int c = 0; c < C; ++c) hv[c] = (_Float16)p[(size_t)c * PLANE];
                if (!INTERIOR) msk[idx] = 1.0f;
            } else {
#pragma unroll
                for (int c = 0; c < C; ++c) hv[c] = (_Float16)0.0f;
                msk[idx] = 0.0f;
            }
            tile[idx] = hv;
        }
    }
    __syncthreads();

    // halo-row origin for this thread: window of px0 starts at halo row 2*ty
    const half8_t* lp = tile + (2 * ty) * SW + tx;
    const half8_t fc0 = lp[3 * SW + 3];  // center of px0
    const half8_t fc1 = lp[4 * SW + 3];  // center of px1

    float a00 = 0.f, a01 = 0.f, a02 = 0.f, ws0 = 0.f;
    float a10 = 0.f, a11 = 0.f, a12 = 0.f, ws1 = 0.f;

    half8_t q0_, q1_, q2_, q3_, q4_, q5_, q6_;

#define LOADROW(I) do { const half8_t* lq_ = lp + (I) * SW;              \
        q0_ = lq_[0]; q1_ = lq_[1]; q2_ = lq_[2]; q3_ = lq_[3];          \
        q4_ = lq_[4]; q5_ = lq_[5]; q6_ = lq_[6]; } while (0)

#define PIXA(Q, J) do {                                                  \
        half8_t d_ = (Q) - fc0;                                          \
        half8_t dd_ = d_ * d_;                                           \
        float lw_ = fmaf((float)(((J) - 3) * ((J) - 3)), sxf0, rs0_);    \
        lw_ = dot2acc(__builtin_shufflevector(dd_, dd_, 0, 1), rp01_0, lw_); \
        lw_ = dot2acc(__builtin_shufflevector(dd_, dd_, 2, 3), rp23_0, lw_); \
        lw_ = dot2acc(__builtin_shufflevector(dd_, dd_, 4, 5), rp45_0, lw_); \
        lw_ = dot2acc(__builtin_shufflevector(dd_, dd_, 6, 7), rp67_0, lw_); \
        float w_ = fast_exp2(lw_);                                       \
        if (!INTERIOR) w_ *= mrow_[(J)];                                 \
        ws0 += w_;                                                       \
        a00 = fmaf(w_, (float)(Q)[0], a00);                              \
        a01 = fmaf(w_, (float)(Q)[1], a01);                              \
        a02 = fmaf(w_, (float)(Q)[2], a02);                              \
    } while (0)

#define PIXB(Q, J) do {                                                  \
        half8_t d_ = (Q) - fc1;                                          \
        half8_t dd_ = d_ * d_;                                           \
        float lw_ = fmaf((float)(((J) - 3) * ((J) - 3)), sxf1, rs1_);    \
        lw_ = dot2acc(__builtin_shufflevector(dd_, dd_, 0, 1), rp01_1, lw_); \
        lw_ = dot2acc(__builtin_shufflevector(dd_, dd_, 2, 3), rp23_1, lw_); \
        lw_ = dot2acc(__builtin_shufflevector(dd_, dd_, 4, 5), rp45_1, lw_); \
        lw_ = dot2acc(__builtin_shufflevector(dd_, dd_, 6, 7), rp67_1, lw_); \
        float w_ = fast_exp2(lw_);                                       \
        if (!INTERIOR) w_ *= mrow_[(J)];                                 \
        ws1 += w_;                                                       \
        a10 = fmaf(w_, (float)(Q)[0], a10);                              \
        a11 = fmaf(w_, (float)(Q)[1], a11);                              \
        a12 = fmaf(w_, (float)(Q)[2], a12);                              \
    } while (0)

#define ROW_COMMON(I)                                                    \
        LOADROW(I);                                                      \
        const float* mrow_ = msk + (2 * ty + (I)) * SW + tx;             \
        (void)mrow_;

#define ROW_FIRST(I) {                                                   \
        ROW_COMMON(I)                                                    \
        const float rs0_ = syf0 * (float)(((I) - 3) * ((I) - 3));        \
        PIXA(q0_, 0); PIXA(q1_, 1); PIXA(q2_, 2); PIXA(q3_, 3);          \
        PIXA(q4_, 4); PIXA(q5_, 5); PIXA(q6_, 6);                        \
    }

#define ROW_BOTH(I) {                                                    \
        ROW_COMMON(I)                                                    \
        const float rs0_ = syf0 * (float)(((I) - 3) * ((I) - 3));        \
        const float rs1_ = syf1 * (float)(((I) - 4) * ((I) - 4));        \
        PIXA(q0_, 0); PIXB(q0_, 0); PIXA(q1_, 1); PIXB(q1_, 1);          \
        PIXA(q2_, 2); PIXB(q2_, 2); PIXA(q3_, 3); PIXB(q3_, 3);          \
        PIXA(q4_, 4); PIXB(q4_, 4); PIXA(q5_, 5); PIXB(q5_, 5);          \
        PIXA(q6_, 6); PIXB(q6_, 6);                                      \
    }

#define ROW_LAST(I) {                                                    \
        ROW_COMMON(I)                                                    \
        const float rs1_ = syf1 * (float)(((I) - 4) * ((I) - 4));        \
        PIXB(q0_, 0); PIXB(q1_, 1); PIXB(q2_, 2); PIXB(q3_, 3);          \
        PIXB(q4_, 4); PIXB(q5_, 5); PIXB(q6_, 6);                        \
    }

    ROW_FIRST(0)
    ROW_BOTH(1)
    ROW_BOTH(2)
    ROW_BOTH(3)
    ROW_BOTH(4)
    ROW_BOTH(5)
    ROW_BOTH(6)
    ROW_LAST(7)

#undef ROW_LAST
#undef ROW_BOTH
#undef ROW_FIRST
#undef ROW_COMMON
#undef PIXB
#undef PIXA
#undef LOADROW

    const float inv0 = 1.0f / ws0;
    const float inv1 = 1.0f / ws1;
    outb[pofs0]                 = a00 * inv0;
    outb[PLANE + pofs0]         = a01 * inv0;
    outb[2 * PLANE + pofs0]     = a02 * inv0;
    outb[pofs0 + W]             = a10 * inv1;
    outb[PLANE + pofs0 + W]     = a11 * inv1;
    outb[2 * PLANE + pofs0 + W] = a12 * inv1;
}

// VGPR-cap model (empirical, this toolchain): launch_bounds(256,N) caps
// VGPRs at 256/N. (256,8)->32 (prev R3, 800MB spill), (256,4)->64 (R3 here:
// 1.18GB spill since 2px body needs ~80 live), so use (256,2)->cap 128.
// HW occupancy then self-sets from actual usage (~512/VGPR waves/SIMD).
__global__ __launch_bounds__(TX * TY, 2) void bilateral_kernel(const float* __restrict__ in,
                                                               float* __restrict__ out)
{
    __shared__ __align__(16) half8_t tile[NPOS];
    __shared__ float msk[NPOS];
    const int b = blockIdx.z;
    const int gx0 = blockIdx.x * TX;
    const int gy0 = blockIdx.y * TILE_H;
    const float* inb = in + (size_t)b * CIN * PLANE;
    float* outb = out + (size_t)b * 3 * PLANE;

    const bool interior = (gx0 >= 3) && (gx0 + TX + 3 <= W) &&
                          (gy0 >= 3) && (gy0 + TILE_H + 3 <= H);
    if (interior)
        run_tile<true>(inb, outb, tile, msk, gy0, gx0);
    else
        run_tile<false>(inb, outb, tile, msk, gy0, gx0);
}

} // namespace

extern "C" void kernel_launch(void* const* d_in, const int* in_sizes, int n_in,
                              void* d_out, int out_size, void* d_ws, size_t ws_size,
                              hipStream_t stream)
{
    const float* in = (const float*)d_in[0];
    float* out = (float*)d_out;
    dim3 grid(W / TX, H / TILE_H, 2);
    dim3 block(TX, TY);
    hipLaunchKernelGGL(bilateral_kernel, grid, block, 0, stream, in, out);
}